// Round 12
// baseline (189.769 us; speedup 1.0000x reference)
//
#include <hip/hip_runtime.h>
#include <math.h>

// Problem constants (fixed by setup_inputs): B=4, H=W=D=128, C=2, fp32.
#define BN 4
#define HN 128
#define WN 128
#define DN 128

// v13 = v12's cross-tile pipeline rebuilt SCRATCH-PROOF.
// v12 NaN diagnosis (rule #20 + async asm): array-held asm-load destinations
// can be demoted to scratch in a big unrolled body; the compiler then spills
// the dest register RIGHT AFTER the asm (it believes the value is already
// there), but the hardware write lands ~500cy later -> garbage round-trip.
// Fix: every asm destination (qa0..qd1), every weight (wxLA0..), every
// address (rA0..) is a NAMED SCALAR; parities A/B and voxels 0/1 are
// hand-unrolled via token pasting. __launch_bounds__(256,1) removes
// occupancy-driven spilling. "=&v" + "memory" clobber as insurance.
//
// Pipeline per block (32j x 128k at fixed (b,i), 8 k-tiles of 16):
//   prologue: AW(A,0); ISSUE;
//   step T:   AW(par(T+1), T+1)   // fp64 addr+weights, overlaps loads(T)
//             vmcnt(0)            // loads(T) landed
//             TAIL(par(T), T)     // combine -> ISSUE(T+1) -> nt-store(T)
// Math = the 7-round-validated folded fp64 path (absmax 1.578125).

typedef float f32x4 __attribute__((ext_vector_type(4)));

#define GLOAD16(dst, ptr) \
    asm volatile("global_load_dwordx4 %0, %1, off" \
                 : "=&v"(dst) : "v"(ptr) : "memory")
#define VMWAIT0() do { \
    __builtin_amdgcn_sched_barrier(0); \
    asm volatile("s_waitcnt vmcnt(0)" ::: "memory"); \
    __builtin_amdgcn_sched_barrier(0); } while (0)

__global__ __launch_bounds__(256, 1) void st_trilerp_kernel(
    const float* __restrict__ image,   // [B*H*W*D, 2] viewed flat
    const float* __restrict__ theta,   // [B, 3, 4]
    float* __restrict__ out)           // [B*H*W*D, 2]
{
    // 2048 blocks = 8 XCDs x 256; chunk swizzle (bijective): XCD x owns a
    // contiguous bi range -> resident blocks share gather planes in its L2.
    const int orig = blockIdx.x;                       // 0..2047
    const int wgid = ((orig & 7) << 8) | (orig >> 3);
    const int bi = wgid >> 2;          // 0..511 = b*H + i (uniform per block)
    const int jt = wgid & 3;           // 0..3
    const int b  = bi >> 7;
    const int i  = bi & (HN - 1);
    const int j0 = jt << 5;            // 32-wide j tile

    const int tid = threadIdx.x;       // 0..255
    const int jj  = tid & 31;          // x-axis fastest across lanes (loads)
    const int kg  = tid >> 5;          // 0..7
    const int j   = j0 + jj;
    const int kbth = kg << 1;          // within-tile k offset (even)

    // np.linspace(-1, 1, 128) float64: v = i*(2/127) - 1, endpoint EXACT.
    const double step = 2.0 / 127.0;
    const double X = (j == WN - 1) ? 1.0 : (double)j * step - 1.0;
    const double Y = (i == HN - 1) ? 1.0 : (double)i * step - 1.0;

    const float* th = theta + b * 12;  // b uniform -> scalar loads
    const double t0 = (double)th[0], t1 = (double)th[1], t2  = (double)th[2],  t3  = (double)th[3];
    const double t4 = (double)th[4], t5 = (double)th[5], t6  = (double)th[6],  t7  = (double)th[7];
    const double t8 = (double)th[8], t9 = (double)th[9], t10 = (double)th[10], t11 = (double)th[11];

    // Folded (validated): coord = P*k + Q
    const double KST = 128.0 / 127.0;
    const double Px = t2  * KST, Qx = fma(64.0, (t0*X + t1*Y) + t3  - t2,  64.0);
    const double Py = t6  * KST, Qy = fma(64.0, (t4*X + t5*Y) + t7  - t6,  64.0);
    const double Pz = t10 * KST, Qz = fma(64.0, (t8*X + t9*Y) + t11 - t10, 64.0);

    const int base = b * (HN * WN * DN);
    const float2* __restrict__ img2 = (const float2*)image;
    const int orow = (bi * WN + j) * DN + kbth;   // float2 units; +T*16 later

    // ---- ALL pipeline state as named scalars (scratch-proof) ----
    float4 qa0, qa1, qb0, qb1, qc0, qc1, qd0, qd1;          // load dests
    int    rA0, rA1, rB0, rB1, rC0, rC1, rD0, rD1;          // addresses
    float  wxLA0, wxLA1, wxLB0, wxLB1, wxHA0, wxHA1, wxHB0, wxHB1;
    float  wy0A0, wy0A1, wy0B0, wy0B1, wy1A0, wy1A1, wy1B0, wy1B1;
    float  wz0A0, wz0A1, wz0B0, wz0B1, wzAA0, wzAA1, wzAB0, wzAB1;

    // One voxel's fp64 coords -> clips -> f32 weights -> addresses.
#define AW1(WS, T, C) do { \
    const double kd = (double)(((T) << 4) + kbth + (C)); \
    const double x = fma(Px, kd, Qx); \
    const double y = fma(Py, kd, Qy); \
    const double z = fma(Pz, kd, Qz); \
    const double xf = floor(x), yf = floor(y), zf = floor(z); \
    const int x0u = (int)xf, y0u = (int)yf, z0u = (int)zf; \
    const int x0 = min(max(x0u,     0), WN - 1); \
    const int x1 = min(max(x0u + 1, 0), WN - 1); \
    const int y0 = min(max(y0u,     0), HN - 1); \
    const int y1 = min(max(y0u + 1, 0), HN - 1); \
    const int z0 = min(max(z0u,     0), DN - 1); \
    const int z1 = min(max(z0u + 1, 0), DN - 1); \
    const float xs = (float)x, ys = (float)y, zs = (float)z; \
    const float wx0f = (float)x1 - xs, wx1f = xs - (float)x0; \
    wy0##WS##C = (float)y1 - ys;  wy1##WS##C = ys - (float)y0; \
    wz0##WS##C = (float)z1 - zs;  wzA##WS##C = (float)(z1 - z0); \
    const int xb  = min(x0, WN - 2); \
    const bool lo0 = (x0 == xb), lo1 = (x1 == xb); \
    wxL##WS##C = (lo0 ? wx0f : 0.0f) + (lo1 ? wx1f : 0.0f); \
    wxH##WS##C = (lo0 ? 0.0f : wx0f) + (lo1 ? 0.0f : wx1f); \
    const int rb = base + (y0 << 7) + (z0 << 14) + xb; \
    const int dy = (y1 - y0) << 7; \
    const int dz = (z1 - z0) << 14; \
    rA##C = rb;      rB##C = rb + dy; \
    rC##C = rb + dz; rD##C = rb + dy + dz; \
} while (0)

#define AW(WS, T) do { AW1(WS, T, 0); AW1(WS, T, 1); } while (0)

#define ISSUE() do { \
    GLOAD16(qa0, img2 + rA0); \
    GLOAD16(qb0, img2 + rB0); \
    GLOAD16(qc0, img2 + rC0); \
    GLOAD16(qd0, img2 + rD0); \
    GLOAD16(qa1, img2 + rA1); \
    GLOAD16(qb1, img2 + rB1); \
    GLOAD16(qc1, img2 + rC1); \
    GLOAD16(qd1, img2 + rD1); \
} while (0)

    // One voxel's combine (validated x-pair weight-select form).
#define COMB1(WS, C) do { \
    const float gax = wxL##WS##C*qa##C.x + wxH##WS##C*qa##C.z; \
    const float gay = wxL##WS##C*qa##C.y + wxH##WS##C*qa##C.w; \
    const float gbx = wxL##WS##C*qb##C.x + wxH##WS##C*qb##C.z; \
    const float gby = wxL##WS##C*qb##C.y + wxH##WS##C*qb##C.w; \
    const float gcx = wxL##WS##C*qc##C.x + wxH##WS##C*qc##C.z; \
    const float gcy = wxL##WS##C*qc##C.y + wxH##WS##C*qc##C.w; \
    const float gdx = wxL##WS##C*qd##C.x + wxH##WS##C*qd##C.z; \
    const float gdy = wxL##WS##C*qd##C.y + wxH##WS##C*qd##C.w; \
    const float h0x = wy0##WS##C*gax + wy1##WS##C*gbx; \
    const float h0y = wy0##WS##C*gay + wy1##WS##C*gby; \
    const float h1x = wy0##WS##C*gcx + wy1##WS##C*gdx; \
    const float h1y = wy0##WS##C*gcy + wy1##WS##C*gdy; \
    ox##C = wz0##WS##C*h0x + wzA##WS##C*h1x; \
    oy##C = wz0##WS##C*h0y + wzA##WS##C*h1y; \
} while (0)

    // Combine both voxels (q dies), optionally issue next tile, nt-store 16B.
#define TAIL(WS, T, DO_ISSUE) do { \
    float ox0, oy0, ox1, oy1; \
    COMB1(WS, 0); \
    COMB1(WS, 1); \
    if (DO_ISSUE) { ISSUE(); } \
    f32x4 val; val.x = ox0; val.y = oy0; val.z = ox1; val.w = oy1; \
    __builtin_nontemporal_store(val, \
        (f32x4*)((float2*)out + orow + ((T) << 4))); \
} while (0)

    // ---- Prologue: tile 0 addresses + gathers in flight ----
    AW(A, 0);
    ISSUE();

    // ---- Pipeline, parities hand-written (tile t: even=A, odd=B) ----
    AW(B, 1); VMWAIT0(); TAIL(A, 0, 1);
    AW(A, 2); VMWAIT0(); TAIL(B, 1, 1);
    AW(B, 3); VMWAIT0(); TAIL(A, 2, 1);
    AW(A, 4); VMWAIT0(); TAIL(B, 3, 1);
    AW(B, 5); VMWAIT0(); TAIL(A, 4, 1);
    AW(A, 6); VMWAIT0(); TAIL(B, 5, 1);
    AW(B, 7); VMWAIT0(); TAIL(A, 6, 1);
    VMWAIT0(); TAIL(B, 7, 0);

#undef TAIL
#undef COMB1
#undef ISSUE
#undef AW
#undef AW1
}

extern "C" void kernel_launch(void* const* d_in, const int* in_sizes, int n_in,
                              void* d_out, int out_size, void* d_ws, size_t ws_size,
                              hipStream_t stream) {
    const float* image = (const float*)d_in[0];
    const float* theta = (const float*)d_in[1];
    float* out = (float*)d_out;

    st_trilerp_kernel<<<dim3(2048), 256, 0, stream>>>(image, theta, out);
}

// Round 13
// 138.219 us; speedup vs baseline: 1.3730x; 1.3730x over previous
//
#include <hip/hip_runtime.h>
#include <math.h>

// Problem constants (fixed by setup_inputs): B=4, H=W=D=128, C=2, fp32.
#define BN 4
#define HN 128
#define WN 128
#define DN 128

// v14: cross-k-tile pipeline with v13's three failure modes removed.
// v13 post-mortem: (1) WRITE_SIZE doubled -- barrier-less wave drift broke
// L2 write-combining of partial-line stores; (2) vmcnt(0) drained the
// interleaved nt-store ACKs every step (serial +200-500cy); (3) VGPR=52 =>
// state not held. v14:
//  - counted VMWAIT(1): the one store after each tile's loads may stay
//    outstanding; in-order vmcnt retirement proves all 8 loads landed.
//    Compiler-inserted vmem can only make the wait stricter (newest-first
//    exclusion), never weaker.
//  - per-tile RAW s_barrier + lgkmcnt(0) fence (8-phase-template pattern):
//    waves stay lockstep -> write-combining restored; LDS double-buffer is
//    race-free (reads of buf[T&1] complete before the reader arrives at
//    barrier(T+1); the next write to that buf is after barrier(T+1)).
//  - v7's proven LDS-transpose coalesced store (full 128B lines/instr).
//  - all pipeline state NAMED SCALARS (v13-validated vs rule #20).
// Per block: 32j x 64k at fixed (b,i) = 4 k-tiles of 16; grid 4096 blocks.
// Step T: AW(T+1) | VMWAIT | COMBINE(T)->LDS | ISSUE(T+1) | lgkm+barrier |
//         READ+nt-store(T).  Loads(T+1) fly over the whole tail.
// Math = the validated folded fp64 path (absmax 1.578125, 8 rounds).

typedef float f32x4 __attribute__((ext_vector_type(4)));

#define GLOAD16(dst, ptr) \
    asm volatile("global_load_dwordx4 %0, %1, off" \
                 : "=&v"(dst) : "v"(ptr) : "memory")
#define VMWAIT(n) do { \
    __builtin_amdgcn_sched_barrier(0); \
    asm volatile("s_waitcnt vmcnt(" #n ")" ::: "memory"); \
    __builtin_amdgcn_sched_barrier(0); } while (0)

__global__ __launch_bounds__(256, 2) void st_trilerp_kernel(
    const float* __restrict__ image,   // [B*H*W*D, 2] viewed flat
    const float* __restrict__ theta,   // [B, 3, 4]
    float* __restrict__ out)           // [B*H*W*D, 2]
{
    const int bi  = blockIdx.z;        // b*H + i  (uniform per block)
    const int b   = bi >> 7;
    const int i   = bi & (HN - 1);
    const int j0  = blockIdx.y << 5;   // 32-wide j tile
    const int kb0 = blockIdx.x << 6;   // 64-wide k range = 4 tiles of 16

    const int tid  = threadIdx.x;      // 0..255
    const int jj   = tid & 31;         // x-axis fastest across lanes (loads)
    const int kg   = tid >> 5;         // 0..7
    const int j    = j0 + jj;
    const int kbth = kg << 1;          // within-tile k offset (even)
    const int kk   = kbth;             // LDS row base
    const int row  = tid >> 3;         // store phase: j row 0..31
    const int col  = tid & 7;          // store phase: float4 column 0..7

    // np.linspace(-1, 1, 128) float64: v = i*(2/127) - 1, endpoint EXACT.
    const double step = 2.0 / 127.0;
    const double X = (j == WN - 1) ? 1.0 : (double)j * step - 1.0;
    const double Y = (i == HN - 1) ? 1.0 : (double)i * step - 1.0;

    const float* th = theta + b * 12;  // b uniform -> scalar loads
    const double t0 = (double)th[0], t1 = (double)th[1], t2  = (double)th[2],  t3  = (double)th[3];
    const double t4 = (double)th[4], t5 = (double)th[5], t6  = (double)th[6],  t7  = (double)th[7];
    const double t8 = (double)th[8], t9 = (double)th[9], t10 = (double)th[10], t11 = (double)th[11];

    // Folded (validated): coord = P*k + Q
    const double KST = 128.0 / 127.0;
    const double Px = t2  * KST, Qx = fma(64.0, (t0*X + t1*Y) + t3  - t2,  64.0);
    const double Py = t6  * KST, Qy = fma(64.0, (t4*X + t5*Y) + t7  - t6,  64.0);
    const double Pz = t10 * KST, Qz = fma(64.0, (t8*X + t9*Y) + t11 - t10, 64.0);

    const int base = b * (HN * WN * DN);
    const float2* __restrict__ img2 = (const float2*)image;
    const int orowS = (bi * WN + (j0 + row)) * DN + kb0;   // store base (float2)

    __shared__ float2 tile[2][16][33];  // double-buffered; pitch 33 breaks pow2

    // ---- ALL pipeline state as named scalars (scratch-proof, v13) ----
    float4 La0, La1, Lb0, Lb1, Lc0, Lc1, Ld0, Ld1;          // load dests
    int    iA0, iA1, iB0, iB1, iC0, iC1, iD0, iD1;          // addresses
    float  wxLA0, wxLA1, wxLB0, wxLB1, wxHA0, wxHA1, wxHB0, wxHB1;
    float  wy0A0, wy0A1, wy0B0, wy0B1, wy1A0, wy1A1, wy1B0, wy1B1;
    float  wz0A0, wz0A1, wz0B0, wz0B1, wzAA0, wzAA1, wzAB0, wzAB1;

    // One voxel's fp64 coords -> clips -> f32 weights -> addresses.
#define AW1(WS, T, C) do { \
    const double kd = (double)(kb0 + ((T) << 4) + kbth + (C)); \
    const double x = fma(Px, kd, Qx); \
    const double y = fma(Py, kd, Qy); \
    const double z = fma(Pz, kd, Qz); \
    const double xf = floor(x), yf = floor(y), zf = floor(z); \
    const int x0u = (int)xf, y0u = (int)yf, z0u = (int)zf; \
    const int x0 = min(max(x0u,     0), WN - 1); \
    const int x1 = min(max(x0u + 1, 0), WN - 1); \
    const int y0 = min(max(y0u,     0), HN - 1); \
    const int y1 = min(max(y0u + 1, 0), HN - 1); \
    const int z0 = min(max(z0u,     0), DN - 1); \
    const int z1 = min(max(z0u + 1, 0), DN - 1); \
    const float xs = (float)x, ys = (float)y, zs = (float)z; \
    const float wx0f = (float)x1 - xs, wx1f = xs - (float)x0; \
    wy0##WS##C = (float)y1 - ys;  wy1##WS##C = ys - (float)y0; \
    wz0##WS##C = (float)z1 - zs;  wzA##WS##C = (float)(z1 - z0); \
    const int xb  = min(x0, WN - 2); \
    const bool lo0 = (x0 == xb), lo1 = (x1 == xb); \
    wxL##WS##C = (lo0 ? wx0f : 0.0f) + (lo1 ? wx1f : 0.0f); \
    wxH##WS##C = (lo0 ? 0.0f : wx0f) + (lo1 ? 0.0f : wx1f); \
    const int rb = base + (y0 << 7) + (z0 << 14) + xb; \
    const int dy = (y1 - y0) << 7; \
    const int dz = (z1 - z0) << 14; \
    iA##C = rb;      iB##C = rb + dy; \
    iC##C = rb + dz; iD##C = rb + dy + dz; \
} while (0)

#define AW(WS, T) do { AW1(WS, T, 0); AW1(WS, T, 1); } while (0)

#define ISSUE() do { \
    GLOAD16(La0, img2 + iA0); \
    GLOAD16(Lb0, img2 + iB0); \
    GLOAD16(Lc0, img2 + iC0); \
    GLOAD16(Ld0, img2 + iD0); \
    GLOAD16(La1, img2 + iA1); \
    GLOAD16(Lb1, img2 + iB1); \
    GLOAD16(Lc1, img2 + iC1); \
    GLOAD16(Ld1, img2 + iD1); \
} while (0)

    // One voxel's combine (validated x-pair weight-select) -> LDS buf.
#define COMB1(WS, C, BUF) do { \
    const float gax = wxL##WS##C*La##C.x + wxH##WS##C*La##C.z; \
    const float gay = wxL##WS##C*La##C.y + wxH##WS##C*La##C.w; \
    const float gbx = wxL##WS##C*Lb##C.x + wxH##WS##C*Lb##C.z; \
    const float gby = wxL##WS##C*Lb##C.y + wxH##WS##C*Lb##C.w; \
    const float gcx = wxL##WS##C*Lc##C.x + wxH##WS##C*Lc##C.z; \
    const float gcy = wxL##WS##C*Lc##C.y + wxH##WS##C*Lc##C.w; \
    const float gdx = wxL##WS##C*Ld##C.x + wxH##WS##C*Ld##C.z; \
    const float gdy = wxL##WS##C*Ld##C.y + wxH##WS##C*Ld##C.w; \
    const float h0x = wy0##WS##C*gax + wy1##WS##C*gbx; \
    const float h0y = wy0##WS##C*gay + wy1##WS##C*gby; \
    const float h1x = wy0##WS##C*gcx + wy1##WS##C*gdx; \
    const float h1y = wy0##WS##C*gcy + wy1##WS##C*gdy; \
    tile[BUF][kk + (C)][jj] = make_float2( \
        wz0##WS##C*h0x + wzA##WS##C*h1x, \
        wz0##WS##C*h0y + wzA##WS##C*h1y); \
} while (0)

    // Coalesced nt-store from LDS (v7's proven full-line pattern).
#define RSTORE(T, BUF) do { \
    const float2 a  = tile[BUF][2*col + 0][row]; \
    const float2 d  = tile[BUF][2*col + 1][row]; \
    f32x4 val; val.x = a.x; val.y = a.y; val.z = d.x; val.w = d.y; \
    __builtin_nontemporal_store(val, \
        (f32x4*)((float2*)out + orowS + ((T) << 4) + 2*col)); \
} while (0)

    // One pipeline step. NWAIT literal: 0 for first tile, 1 after (the one
    // nt-store issued after each tile's loads may stay outstanding).
#define STEP(WS, T, BUF, NWAIT, DO_ISSUE) do { \
    VMWAIT(NWAIT); \
    COMB1(WS, 0, BUF); \
    COMB1(WS, 1, BUF); \
    if (DO_ISSUE) { ISSUE(); } \
    asm volatile("s_waitcnt lgkmcnt(0)" ::: "memory"); \
    __builtin_amdgcn_sched_barrier(0); \
    __builtin_amdgcn_s_barrier();      /* raw: in-flight loads cross it */ \
    __builtin_amdgcn_sched_barrier(0); \
    RSTORE(T, BUF); \
} while (0)

    // ---- Prologue: tile 0 addresses + gathers in flight ----
    AW(A, 0);
    ISSUE();

    // ---- Pipeline: AW(T+1) overlaps loads(T); parities hand-written ----
    AW(B, 1); STEP(A, 0, 0, 0, 1);
    AW(A, 2); STEP(B, 1, 1, 1, 1);
    AW(B, 3); STEP(A, 2, 0, 1, 1);
              STEP(B, 3, 1, 1, 0);

#undef STEP
#undef RSTORE
#undef COMB1
#undef ISSUE
#undef AW
#undef AW1
}

extern "C" void kernel_launch(void* const* d_in, const int* in_sizes, int n_in,
                              void* d_out, int out_size, void* d_ws, size_t ws_size,
                              hipStream_t stream) {
    const float* image = (const float*)d_in[0];
    const float* theta = (const float*)d_in[1];
    float* out = (float*)d_out;

    dim3 grid(DN / 64, WN / 32, BN * HN);   // (2, 4, 512) = 4096 blocks
    st_trilerp_kernel<<<grid, 256, 0, stream>>>(image, theta, out);
}